// Round 20
// baseline (517.516 us; speedup 1.0000x reference)
//
#include <hip/hip_runtime.h>
#include <hip/hip_bf16.h>
#include <math.h>

#define NB 16384
#define NH 16
#define ND 256
#define NM 1024
#define BM 128           // rows per block
#define MB 64            // m-chunk
#define NCH (NM / MB)    // 16

typedef float f32x4 __attribute__((ext_vector_type(4)));
typedef float f32x16 __attribute__((ext_vector_type(16)));
typedef short bf16x8 __attribute__((ext_vector_type(8)));
typedef unsigned short u16;
typedef unsigned int u32;

__device__ __forceinline__ u16 f2bf(float f) {
  union { float f; unsigned u; } v; v.f = f;
  unsigned r = v.u + 0x7FFFu + ((v.u >> 16) & 1u);
  return (u16)(r >> 16);
}

// UpF[h]: granule byte off = mc*32768 + kh*1024 + m*16, kh in [0,32), m in [0,64)
//   elems e: up[h][kh*8+e][mc*64+m]   (up fp32 [H][256][1024])
__global__ __launch_bounds__(256) void prep_up(const float* __restrict__ src,
                                               u16* __restrict__ dst) {
  __shared__ float tile[64][65];
  const int h = blockIdx.z;
  const int m0 = blockIdx.x * 64, d0 = blockIdx.y * 64;
  const int tr = threadIdx.x >> 6, tc = threadIdx.x & 63;
  const float* s = src + (size_t)h * ND * NM;
#pragma unroll
  for (int i = 0; i < 16; ++i) {
    int r = i * 4 + tr;
    tile[r][tc] = s[(size_t)(d0 + r) * NM + m0 + tc];
  }
  __syncthreads();
  char* dh = (char*)dst + (size_t)h * NM * ND * 2;
#pragma unroll
  for (int g = 0; g < 2; ++g) {
    int gi = g * 256 + threadIdx.x;
    int kh_l = gi >> 6, m_l = gi & 63;
    bf16x8 o;
#pragma unroll
    for (int e = 0; e < 8; ++e) o[e] = (short)f2bf(tile[kh_l * 8 + e][m_l]);
    *(bf16x8*)(dh + (size_t)(m0 >> 6) * 32768 + (size_t)((d0 >> 3) + kh_l) * 1024 + m_l * 16) = o;
  }
}

// DownF[h]: granule byte off = mc*32768 + kh*4096 + d*16, kh in [0,8), d in [0,256)
//   elems e: down[h][mc*64+kh*8+e][d]   (down fp32 [H][1024][256])
__global__ __launch_bounds__(256) void prep_down(const float* __restrict__ src,
                                                 u16* __restrict__ dst) {
  __shared__ float tile[64][65];
  const int h = blockIdx.z;
  const int mc = blockIdx.x, d0 = blockIdx.y * 64;
  const int tr = threadIdx.x >> 6, tc = threadIdx.x & 63;
  const float* s = src + (size_t)h * NM * ND;
#pragma unroll
  for (int i = 0; i < 16; ++i) {
    int r = i * 4 + tr;
    tile[r][tc] = s[(size_t)(mc * 64 + r) * ND + d0 + tc];
  }
  __syncthreads();
  char* dh = (char*)dst + (size_t)h * NM * ND * 2;
#pragma unroll
  for (int g = 0; g < 2; ++g) {
    int gi = g * 256 + threadIdx.x;
    int kh_l = gi >> 6, d_l = gi & 63;
    bf16x8 o;
#pragma unroll
    for (int e = 0; e < 8; ++e) o[e] = (short)f2bf(tile[kh_l * 8 + e][d_l]);
    *(bf16x8*)(dh + (size_t)mc * 32768 + (size_t)kh_l * 4096 + (size_t)(d0 + d_l) * 16) = o;
  }
}

// xp[b][i] = bf16(x[b][perm[i]])
__global__ __launch_bounds__(1024) void permute_x(const float* __restrict__ x,
                                                  const int* __restrict__ perm,
                                                  u16* __restrict__ xp) {
  const int b = blockIdx.x;
  const int t = threadIdx.x;
  const float* xr = x + (size_t)b * 4096;
  int4 p = *(const int4*)(perm + t * 4);
  ushort4 o;
  o.x = f2bf(xr[p.x]); o.y = f2bf(xr[p.y]);
  o.z = f2bf(xr[p.z]); o.w = f2bf(xr[p.w]);
  *(ushort4*)(xp + (size_t)b * 4096 + t * 4) = o;
}

// out[b][j] = fp32(pre[b][unperm[j]]); pre is the bf16 pre-unpermute output
// that mlp_fused wrote back into the xp buffer.
__global__ __launch_bounds__(1024) void unpermute_cvt(const u16* __restrict__ pre,
                                                      const int* __restrict__ unperm,
                                                      float* __restrict__ out) {
  __shared__ u16 row[4096];
  const int b = blockIdx.x;
  const int t = threadIdx.x;
  const u16* prow = pre + (size_t)b * 4096;
  *(ushort4*)(row + t * 4) = *(const ushort4*)(prow + t * 4);
  __syncthreads();
  int4 u = *(const int4*)(unperm + t * 4);
  f32x4 v;
  union { u32 u; float f; } c0, c1, c2, c3;
  c0.u = (u32)row[u.x] << 16; c1.u = (u32)row[u.y] << 16;
  c2.u = (u32)row[u.z] << 16; c3.u = (u32)row[u.w] << 16;
  v.x = c0.f; v.y = c1.f; v.z = c2.f; v.w = c3.f;
  *(f32x4*)(out + (size_t)b * 4096 + t * 4) = v;
}

// 16-wave PRODUCER/CONSUMER MLP -- R19 (353us, clean counters) + two
// A-wave critical-path cuts using A's spare accum quota:
//  (1) pa split into 2 independent chains (even/odd ks; +16 accum, free):
//      halves the dependent-MFMA latency exposure (~150cy -> ~75cy) and
//      lets the scheduler interleave the chains' ds_reads.
//  (2) GELU 7-op quadratic-tanh -> 5-op sigmoid v*sigma(1.702v)
//      (exp2(2.4554670*v)); max err ~0.02/value -> ~+0.6 absmax after the
//      1024-wide down-proj (threshold 48.6, current 8.0 -- safe).
// Hybrid X residency (R19-verified): xr[8] resident (32 arch), K-high-half
// re-loaded from L2 each chunk in two sched_barrier-pinned groups of 4.
// B-branch, staging, barriers, Ps layout, bf16-epilogue: verbatim R19/R15.
__global__ __launch_bounds__(1024, 4) void mlp_fused(
    u16* __restrict__ xp,
    const u16* __restrict__ upF,
    const u16* __restrict__ downF) {
  __shared__ __align__(16) u16 Us[2][MB * ND];   // 2x32KB [kh32][m64][8]
  __shared__ __align__(16) u16 Ds[2][ND * MB];   // 2x32KB [kh8][d256][8]
  __shared__ __align__(16) u16 Ps[2][BM * MB];   // 2x16KB [kh8][r128][8]

  const int h   = blockIdx.y;
  const int rb  = blockIdx.x;
  const int tid = threadIdx.x;
  const int w   = tid >> 6;
  const int l   = tid & 63;
  const int lo  = l & 31;
  const int hi  = l >> 5;
  const int row0 = rb * BM;

  const char* upH = (const char*)upF + (size_t)h * NM * ND * 2;
  const char* dnH = (const char*)downF + (size_t)h * NM * ND * 2;

  // ---- prologue: all 16 waves stage Us(0) (2 insts/thread), then barrier
  {
#pragma unroll
    for (int i = 0; i < 2; ++i) {
      int t = i * 1024 + tid;
      __builtin_amdgcn_global_load_lds(
          (const __attribute__((address_space(1))) void*)(upH + (size_t)t * 16),
          (__attribute__((address_space(3))) void*)((char*)&Us[0][0] + (size_t)t * 16),
          16, 0, 0);
    }
  }
  asm volatile("s_waitcnt vmcnt(0)" ::: "memory");
  __builtin_amdgcn_s_barrier();

  if (w < 8) {
    // ================= producer (A): 32x32x16, hybrid X =================
    const int rtA = w & 3;    // 32-row tile
    const int mt  = w >> 2;   // 32-m tile of the 64-m chunk

    // X row base (global): lane = x-row (rtA*32+lo); k = ks*16 + hi*8 + e.
    const char* const px =
        (const char*)(xp + (size_t)(row0 + rtA * 32 + lo) * 4096 + h * ND);
    // Resident low-half fragments: ks = 0..7. 32 VGPR.
    bf16x8 xr[8];
#pragma unroll
    for (int ks = 0; ks < 8; ++ks)
      xr[ks] = *(const bf16x8*)(px + ks * 32 + hi * 16);

    char* const psW = (char*)&Ps[0][0] + (size_t)(rtA * 32 + lo) * 16 + hi * 8;

    for (int i = 0; i < NCH; ++i) {
      const int c = i & 1;

      // high-half X group 1 (ks 8..11) -- issued before staging so the
      // compiler's auto-wait before use counts only the 4 stage loads.
      bf16x8 xv0 = *(const bf16x8*)(px + 8 * 32 + hi * 16);
      bf16x8 xv1 = *(const bf16x8*)(px + 9 * 32 + hi * 16);
      bf16x8 xv2 = *(const bf16x8*)(px + 10 * 32 + hi * 16);
      bf16x8 xv3 = *(const bf16x8*)(px + 11 * 32 + hi * 16);

      // stage Us(i+1) -> buf c^1 (A-threads: tid in [0,512), 4 insts)
      if (i + 1 < NCH) {
        const char* src = upH + (size_t)(i + 1) * 32768;
#pragma unroll
        for (int j = 0; j < 4; ++j) {
          int t = j * 512 + tid;
          __builtin_amdgcn_global_load_lds(
              (const __attribute__((address_space(1))) void*)(src + (size_t)t * 16),
              (__attribute__((address_space(3))) void*)((char*)&Us[c ^ 1][0] + (size_t)t * 16),
              16, 0, 0);
        }
      }

      // A(i): P^T[32m x 32r] = Up-frags @ X-frags, TWO independent chains
      f32x16 pa0, pa1;
#pragma unroll
      for (int e = 0; e < 16; ++e) { pa0[e] = 0.f; pa1[e] = 0.f; }
      {
        const char* ub = (const char*)&Us[c][0] + (size_t)(mt * 32 + lo) * 16 + hi * 1024;
        __builtin_amdgcn_s_setprio(1);
#pragma unroll
        for (int kk = 0; kk < 4; ++kk) {
          bf16x8 av0 = *(const bf16x8*)(ub + (size_t)(2 * kk) * 2048);
          bf16x8 av1 = *(const bf16x8*)(ub + (size_t)(2 * kk + 1) * 2048);
          pa0 = __builtin_amdgcn_mfma_f32_32x32x16_bf16(av0, xr[2 * kk], pa0, 0, 0, 0);
          pa1 = __builtin_amdgcn_mfma_f32_32x32x16_bf16(av1, xr[2 * kk + 1], pa1, 0, 0, 0);
        }
        // group-1 high half (compiler inserts counted vmcnt before first use)
        pa0 = __builtin_amdgcn_mfma_f32_32x32x16_bf16(
            *(const bf16x8*)(ub + (size_t)8 * 2048), xv0, pa0, 0, 0, 0);
        pa1 = __builtin_amdgcn_mfma_f32_32x32x16_bf16(
            *(const bf16x8*)(ub + (size_t)9 * 2048), xv1, pa1, 0, 0, 0);
        pa0 = __builtin_amdgcn_mfma_f32_32x32x16_bf16(
            *(const bf16x8*)(ub + (size_t)10 * 2048), xv2, pa0, 0, 0, 0);
        pa1 = __builtin_amdgcn_mfma_f32_32x32x16_bf16(
            *(const bf16x8*)(ub + (size_t)11 * 2048), xv3, pa1, 0, 0, 0);
        // group-2 loads pinned here (caps live xv at 4 -> arch fits)
        __builtin_amdgcn_sched_barrier(0);
        bf16x8 xw0 = *(const bf16x8*)(px + 12 * 32 + hi * 16);
        bf16x8 xw1 = *(const bf16x8*)(px + 13 * 32 + hi * 16);
        bf16x8 xw2 = *(const bf16x8*)(px + 14 * 32 + hi * 16);
        bf16x8 xw3 = *(const bf16x8*)(px + 15 * 32 + hi * 16);
        pa0 = __builtin_amdgcn_mfma_f32_32x32x16_bf16(
            *(const bf16x8*)(ub + (size_t)12 * 2048), xw0, pa0, 0, 0, 0);
        pa1 = __builtin_amdgcn_mfma_f32_32x32x16_bf16(
            *(const bf16x8*)(ub + (size_t)13 * 2048), xw1, pa1, 0, 0, 0);
        pa0 = __builtin_amdgcn_mfma_f32_32x32x16_bf16(
            *(const bf16x8*)(ub + (size_t)14 * 2048), xw2, pa0, 0, 0, 0);
        pa1 = __builtin_amdgcn_mfma_f32_32x32x16_bf16(
            *(const bf16x8*)(ub + (size_t)15 * 2048), xw3, pa1, 0, 0, 0);
        __builtin_amdgcn_s_setprio(0);
      }

      // gelu (5-op sigmoid form) -> pack -> 4x ds_write_b64 into Ps[c]
      // value v = pa0[4g+e]+pa1[4g+e] = P[r=rtA*32+lo][m = mt*32+g*8+hi*4+e]
#pragma unroll
      for (int g = 0; g < 4; ++g) {
        float gv[4];
#pragma unroll
        for (int e = 0; e < 4; ++e) {
          float v = pa0[g * 4 + e] + pa1[g * 4 + e];
          float ex = __builtin_amdgcn_exp2f(2.4554670f * v);
          float r = __builtin_amdgcn_rcpf(ex + 1.0f);
          gv[e] = __builtin_fmaf(-v, r, v);
        }
        u32 w0, w1;
        asm("v_cvt_pk_bf16_f32 %0, %1, %2" : "=v"(w0) : "v"(gv[0]), "v"(gv[1]));
        asm("v_cvt_pk_bf16_f32 %0, %1, %2" : "=v"(w1) : "v"(gv[2]), "v"(gv[3]));
        uint2 pk; pk.x = w0; pk.y = w1;
        *(uint2*)(psW + (size_t)c * (BM * MB * 2) + (size_t)(mt * 4 + g) * 2048) = pk;
      }

      __builtin_amdgcn_sched_barrier(0);
      asm volatile("s_waitcnt lgkmcnt(0)" ::: "memory");   // Ps published
      asm volatile("s_waitcnt vmcnt(0)" ::: "memory");     // Us(i+1) landed
      __builtin_amdgcn_s_barrier();
      __builtin_amdgcn_sched_barrier(0);
    }
    // A-waves done (pre-out written by B-waves)
  } else {
    // ================= consumer (B): verbatim R15 =================
    const int wb  = w - 8;
    const int rtp = wb & 1;   // 64-row half
    const int dq  = wb >> 1;  // 64-d quarter
    const int tb  = tid - 512;

    f32x16 ca[2][2];   // [rt2][dt] 32x32 tiles: 64r x 64d -> 64 accum
#pragma unroll
    for (int rt2 = 0; rt2 < 2; ++rt2)
#pragma unroll
      for (int dt = 0; dt < 2; ++dt)
#pragma unroll
        for (int e = 0; e < 16; ++e)
          ca[rt2][dt][e] = 0.f;

    for (int i = 0; i < NCH; ++i) {
      const int c = i & 1;
      // stage Ds(i) -> buf c (B-threads, 4 insts)
      {
        const char* src = dnH + (size_t)i * 32768;
#pragma unroll
        for (int j = 0; j < 4; ++j) {
          int t = j * 512 + tb;
          __builtin_amdgcn_global_load_lds(
              (const __attribute__((address_space(1))) void*)(src + (size_t)t * 16),
              (__attribute__((address_space(3))) void*)((char*)&Ds[c][0] + (size_t)t * 16),
              16, 0, 0);
        }
      }

      // B(i-1): C += Ps[c^1] @ Ds[c^1]
      if (i > 0) {
        const char* psb = (const char*)&Ps[c ^ 1][0];
        const char* dsb = (const char*)&Ds[c ^ 1][0];
        __builtin_amdgcn_s_setprio(1);
#pragma unroll
        for (int ks = 0; ks < 4; ++ks) {
          const size_t khp = (size_t)(ks * 2 + hi);
          bf16x8 a0 = *(const bf16x8*)(psb + khp * 2048 + (size_t)(rtp * 64 + lo) * 16);
          bf16x8 a1 = *(const bf16x8*)(psb + khp * 2048 + (size_t)(rtp * 64 + 32 + lo) * 16);
#pragma unroll
          for (int dt = 0; dt < 2; ++dt) {
            bf16x8 bv = *(const bf16x8*)(dsb + khp * 4096 + (size_t)(dq * 64 + dt * 32 + lo) * 16);
            ca[0][dt] = __builtin_amdgcn_mfma_f32_32x32x16_bf16(a0, bv, ca[0][dt], 0, 0, 0);
            ca[1][dt] = __builtin_amdgcn_mfma_f32_32x32x16_bf16(a1, bv, ca[1][dt], 0, 0, 0);
          }
        }
        __builtin_amdgcn_s_setprio(0);
      }

      __builtin_amdgcn_sched_barrier(0);
      asm volatile("s_waitcnt vmcnt(0)" ::: "memory");     // Ds(i) landed
      __builtin_amdgcn_s_barrier();
      __builtin_amdgcn_sched_barrier(0);
    }

    // final B(NCH-1): Ps[1], Ds[1]
    {
      const int c = (NCH - 1) & 1;
      const char* psb = (const char*)&Ps[c][0];
      const char* dsb = (const char*)&Ds[c][0];
      __builtin_amdgcn_s_setprio(1);
#pragma unroll
      for (int ks = 0; ks < 4; ++ks) {
        const size_t khp = (size_t)(ks * 2 + hi);
        bf16x8 a0 = *(const bf16x8*)(psb + khp * 2048 + (size_t)(rtp * 64 + lo) * 16);
        bf16x8 a1 = *(const bf16x8*)(psb + khp * 2048 + (size_t)(rtp * 64 + 32 + lo) * 16);
#pragma unroll
        for (int dt = 0; dt < 2; ++dt) {
          bf16x8 bv = *(const bf16x8*)(dsb + khp * 4096 + (size_t)(dq * 64 + dt * 32 + lo) * 16);
          ca[0][dt] = __builtin_amdgcn_mfma_f32_32x32x16_bf16(a0, bv, ca[0][dt], 0, 0, 0);
          ca[1][dt] = __builtin_amdgcn_mfma_f32_32x32x16_bf16(a1, bv, ca[1][dt], 0, 0, 0);
        }
      }
      __builtin_amdgcn_s_setprio(0);
    }

    // epilogue: bf16 pre-out into the xp buffer (coalesced u16 stores).
    // C-layout 32x32: col d = lo, row = (reg&3) + 8*(reg>>2) + 4*hi.
#pragma unroll
    for (int rt2 = 0; rt2 < 2; ++rt2)
#pragma unroll
      for (int dt = 0; dt < 2; ++dt) {
        const int d = h * ND + dq * 64 + dt * 32 + lo;
#pragma unroll
        for (int reg = 0; reg < 16; ++reg) {
          int r = rtp * 64 + rt2 * 32 + (reg & 3) + 8 * (reg >> 2) + 4 * hi;
          xp[(size_t)(row0 + r) * 4096 + d] = f2bf(ca[rt2][dt][reg]);
        }
      }
  }
}

extern "C" void kernel_launch(void* const* d_in, const int* in_sizes, int n_in,
                              void* d_out, int out_size, void* d_ws, size_t ws_size,
                              hipStream_t stream) {
  const float* x    = (const float*)d_in[0];
  const float* up   = (const float*)d_in[1];
  const float* down = (const float*)d_in[2];
  const int* perm   = (const int*)d_in[3];
  const int* unperm = (const int*)d_in[4];
  float* out = (float*)d_out;

  u16* upF   = (u16*)d_ws;                                   // 8 MB
  u16* downF = upF + (size_t)NH * NM * ND;                   // 8 MB
  u16* xp    = downF + (size_t)NH * NM * ND;                 // 128 MB (xp, then pre-out)

  // weights -> fragment-granule order (one-time, coalesced tile transposes)
  prep_up<<<dim3(NM / 64, ND / 64, NH), 256, 0, stream>>>(up, upF);
  prep_down<<<dim3(NM / 64, ND / 64, NH), 256, 0, stream>>>(down, downF);
  // xp[b][i] = bf16(x[b][perm[i]])
  permute_x<<<NB, 1024, 0, stream>>>(x, perm, xp);
  // main fused MLP: 1024 thr (8 hybrid-X producers + 8 consumers), 160KB.
  mlp_fused<<<dim3(NB / BM, NH), 1024, 0, stream>>>(xp, upF, downF);
  // unpermute + bf16->fp32 cvt into the real output
  unpermute_cvt<<<NB, 1024, 0, stream>>>(xp, unperm, out);
}

// Round 21
// 500.334 us; speedup vs baseline: 1.0343x; 1.0343x over previous
//
#include <hip/hip_runtime.h>
#include <hip/hip_bf16.h>
#include <math.h>

#define NB 16384
#define NH 16
#define ND 256
#define NM 1024
#define BM 128           // rows per block
#define MB 64            // m-chunk
#define NCH (NM / MB)    // 16

typedef float f32x4 __attribute__((ext_vector_type(4)));
typedef float f32x16 __attribute__((ext_vector_type(16)));
typedef short bf16x8 __attribute__((ext_vector_type(8)));
typedef unsigned short u16;
typedef unsigned int u32;

__device__ __forceinline__ u16 f2bf(float f) {
  union { float f; unsigned u; } v; v.f = f;
  unsigned r = v.u + 0x7FFFu + ((v.u >> 16) & 1u);
  return (u16)(r >> 16);
}

// UpF[h]: granule byte off = mc*32768 + kh*1024 + m*16, kh in [0,32), m in [0,64)
//   elems e: up[h][kh*8+e][mc*64+m]   (up fp32 [H][256][1024])
__global__ __launch_bounds__(256) void prep_up(const float* __restrict__ src,
                                               u16* __restrict__ dst) {
  __shared__ float tile[64][65];
  const int h = blockIdx.z;
  const int m0 = blockIdx.x * 64, d0 = blockIdx.y * 64;
  const int tr = threadIdx.x >> 6, tc = threadIdx.x & 63;
  const float* s = src + (size_t)h * ND * NM;
#pragma unroll
  for (int i = 0; i < 16; ++i) {
    int r = i * 4 + tr;
    tile[r][tc] = s[(size_t)(d0 + r) * NM + m0 + tc];
  }
  __syncthreads();
  char* dh = (char*)dst + (size_t)h * NM * ND * 2;
#pragma unroll
  for (int g = 0; g < 2; ++g) {
    int gi = g * 256 + threadIdx.x;
    int kh_l = gi >> 6, m_l = gi & 63;
    bf16x8 o;
#pragma unroll
    for (int e = 0; e < 8; ++e) o[e] = (short)f2bf(tile[kh_l * 8 + e][m_l]);
    *(bf16x8*)(dh + (size_t)(m0 >> 6) * 32768 + (size_t)((d0 >> 3) + kh_l) * 1024 + m_l * 16) = o;
  }
}

// DownF[h]: granule byte off = mc*32768 + kh*4096 + d*16, kh in [0,8), d in [0,256)
//   elems e: down[h][mc*64+kh*8+e][d]   (down fp32 [H][1024][256])
__global__ __launch_bounds__(256) void prep_down(const float* __restrict__ src,
                                                 u16* __restrict__ dst) {
  __shared__ float tile[64][65];
  const int h = blockIdx.z;
  const int mc = blockIdx.x, d0 = blockIdx.y * 64;
  const int tr = threadIdx.x >> 6, tc = threadIdx.x & 63;
  const float* s = src + (size_t)h * NM * ND;
#pragma unroll
  for (int i = 0; i < 16; ++i) {
    int r = i * 4 + tr;
    tile[r][tc] = s[(size_t)(mc * 64 + r) * ND + d0 + tc];
  }
  __syncthreads();
  char* dh = (char*)dst + (size_t)h * NM * ND * 2;
#pragma unroll
  for (int g = 0; g < 2; ++g) {
    int gi = g * 256 + threadIdx.x;
    int kh_l = gi >> 6, d_l = gi & 63;
    bf16x8 o;
#pragma unroll
    for (int e = 0; e < 8; ++e) o[e] = (short)f2bf(tile[kh_l * 8 + e][d_l]);
    *(bf16x8*)(dh + (size_t)mc * 32768 + (size_t)kh_l * 4096 + (size_t)(d0 + d_l) * 16) = o;
  }
}

// xp[b][i] = bf16(x[b][perm[i]])
__global__ __launch_bounds__(1024) void permute_x(const float* __restrict__ x,
                                                  const int* __restrict__ perm,
                                                  u16* __restrict__ xp) {
  const int b = blockIdx.x;
  const int t = threadIdx.x;
  const float* xr = x + (size_t)b * 4096;
  int4 p = *(const int4*)(perm + t * 4);
  ushort4 o;
  o.x = f2bf(xr[p.x]); o.y = f2bf(xr[p.y]);
  o.z = f2bf(xr[p.z]); o.w = f2bf(xr[p.w]);
  *(ushort4*)(xp + (size_t)b * 4096 + t * 4) = o;
}

// out[b][j] = fp32(pre[b][unperm[j]]); pre is the bf16 pre-unpermute output
// that mlp_fused wrote back into the xp buffer.
__global__ __launch_bounds__(1024) void unpermute_cvt(const u16* __restrict__ pre,
                                                      const int* __restrict__ unperm,
                                                      float* __restrict__ out) {
  __shared__ u16 row[4096];
  const int b = blockIdx.x;
  const int t = threadIdx.x;
  const u16* prow = pre + (size_t)b * 4096;
  *(ushort4*)(row + t * 4) = *(const ushort4*)(prow + t * 4);
  __syncthreads();
  int4 u = *(const int4*)(unperm + t * 4);
  f32x4 v;
  union { u32 u; float f; } c0, c1, c2, c3;
  c0.u = (u32)row[u.x] << 16; c1.u = (u32)row[u.y] << 16;
  c2.u = (u32)row[u.z] << 16; c3.u = (u32)row[u.w] << 16;
  v.x = c0.f; v.y = c1.f; v.z = c2.f; v.w = c3.f;
  *(f32x4*)(out + (size_t)b * 4096 + t * 4) = v;
}

// 16-wave PRODUCER/CONSUMER MLP -- R19 structure VERBATIM (353us, clean
// counters: VGPR 64, FETCH 131K, WRITE 132K) with ONE change: GELU switched
// to the 5-op sigmoid form v*sigma(1.702v) (exp2(2.4554670*v)). R20's A/B
// de-confound: the pa0/pa1 split (+16 accum live through GELU) reintroduced
// a ~50MB scratch spill (WRITE 184K) costing +11us, while the GELU swap cut
// VALUBusy 31->27.5. Keep the VALU win, drop the spill: single chain-16 pa
// (16 accum, R19-proven), 5-op GELU (one FEWER temp than R19's 7-op form).
// Hybrid X residency (R19): xr[8] resident (32 arch), K-high-half re-loaded
// from L2 each chunk in two sched_barrier-pinned groups of 4.
// B-branch, staging, barriers, Ps layout, bf16-epilogue: verbatim R15/R19.
__global__ __launch_bounds__(1024, 4) void mlp_fused(
    u16* __restrict__ xp,
    const u16* __restrict__ upF,
    const u16* __restrict__ downF) {
  __shared__ __align__(16) u16 Us[2][MB * ND];   // 2x32KB [kh32][m64][8]
  __shared__ __align__(16) u16 Ds[2][ND * MB];   // 2x32KB [kh8][d256][8]
  __shared__ __align__(16) u16 Ps[2][BM * MB];   // 2x16KB [kh8][r128][8]

  const int h   = blockIdx.y;
  const int rb  = blockIdx.x;
  const int tid = threadIdx.x;
  const int w   = tid >> 6;
  const int l   = tid & 63;
  const int lo  = l & 31;
  const int hi  = l >> 5;
  const int row0 = rb * BM;

  const char* upH = (const char*)upF + (size_t)h * NM * ND * 2;
  const char* dnH = (const char*)downF + (size_t)h * NM * ND * 2;

  // ---- prologue: all 16 waves stage Us(0) (2 insts/thread), then barrier
  {
#pragma unroll
    for (int i = 0; i < 2; ++i) {
      int t = i * 1024 + tid;
      __builtin_amdgcn_global_load_lds(
          (const __attribute__((address_space(1))) void*)(upH + (size_t)t * 16),
          (__attribute__((address_space(3))) void*)((char*)&Us[0][0] + (size_t)t * 16),
          16, 0, 0);
    }
  }
  asm volatile("s_waitcnt vmcnt(0)" ::: "memory");
  __builtin_amdgcn_s_barrier();

  if (w < 8) {
    // ================= producer (A): 32x32x16, hybrid X =================
    const int rtA = w & 3;    // 32-row tile
    const int mt  = w >> 2;   // 32-m tile of the 64-m chunk

    // X row base (global): lane = x-row (rtA*32+lo); k = ks*16 + hi*8 + e.
    const char* const px =
        (const char*)(xp + (size_t)(row0 + rtA * 32 + lo) * 4096 + h * ND);
    // Resident low-half fragments: ks = 0..7. 32 VGPR.
    bf16x8 xr[8];
#pragma unroll
    for (int ks = 0; ks < 8; ++ks)
      xr[ks] = *(const bf16x8*)(px + ks * 32 + hi * 16);

    char* const psW = (char*)&Ps[0][0] + (size_t)(rtA * 32 + lo) * 16 + hi * 8;

    for (int i = 0; i < NCH; ++i) {
      const int c = i & 1;

      // high-half X group 1 (ks 8..11) -- issued before staging so the
      // compiler's auto-wait before use counts only the 4 stage loads.
      bf16x8 xv0 = *(const bf16x8*)(px + 8 * 32 + hi * 16);
      bf16x8 xv1 = *(const bf16x8*)(px + 9 * 32 + hi * 16);
      bf16x8 xv2 = *(const bf16x8*)(px + 10 * 32 + hi * 16);
      bf16x8 xv3 = *(const bf16x8*)(px + 11 * 32 + hi * 16);

      // stage Us(i+1) -> buf c^1 (A-threads: tid in [0,512), 4 insts)
      if (i + 1 < NCH) {
        const char* src = upH + (size_t)(i + 1) * 32768;
#pragma unroll
        for (int j = 0; j < 4; ++j) {
          int t = j * 512 + tid;
          __builtin_amdgcn_global_load_lds(
              (const __attribute__((address_space(1))) void*)(src + (size_t)t * 16),
              (__attribute__((address_space(3))) void*)((char*)&Us[c ^ 1][0] + (size_t)t * 16),
              16, 0, 0);
        }
      }

      // A(i): P^T[32m x 32r] = Up-frags @ X-frags, chain-16 (R19-proven)
      f32x16 pa;
#pragma unroll
      for (int e = 0; e < 16; ++e) pa[e] = 0.f;
      {
        const char* ub = (const char*)&Us[c][0] + (size_t)(mt * 32 + lo) * 16 + hi * 1024;
        __builtin_amdgcn_s_setprio(1);
#pragma unroll
        for (int ks = 0; ks < 8; ++ks) {
          bf16x8 av = *(const bf16x8*)(ub + (size_t)ks * 2048);
          pa = __builtin_amdgcn_mfma_f32_32x32x16_bf16(av, xr[ks], pa, 0, 0, 0);
        }
        // group-1 high half (compiler inserts counted vmcnt before first use)
        pa = __builtin_amdgcn_mfma_f32_32x32x16_bf16(
            *(const bf16x8*)(ub + (size_t)8 * 2048), xv0, pa, 0, 0, 0);
        pa = __builtin_amdgcn_mfma_f32_32x32x16_bf16(
            *(const bf16x8*)(ub + (size_t)9 * 2048), xv1, pa, 0, 0, 0);
        pa = __builtin_amdgcn_mfma_f32_32x32x16_bf16(
            *(const bf16x8*)(ub + (size_t)10 * 2048), xv2, pa, 0, 0, 0);
        pa = __builtin_amdgcn_mfma_f32_32x32x16_bf16(
            *(const bf16x8*)(ub + (size_t)11 * 2048), xv3, pa, 0, 0, 0);
        // group-2 loads pinned here (caps live xv at 4 -> arch fits)
        __builtin_amdgcn_sched_barrier(0);
        bf16x8 xw0 = *(const bf16x8*)(px + 12 * 32 + hi * 16);
        bf16x8 xw1 = *(const bf16x8*)(px + 13 * 32 + hi * 16);
        bf16x8 xw2 = *(const bf16x8*)(px + 14 * 32 + hi * 16);
        bf16x8 xw3 = *(const bf16x8*)(px + 15 * 32 + hi * 16);
        pa = __builtin_amdgcn_mfma_f32_32x32x16_bf16(
            *(const bf16x8*)(ub + (size_t)12 * 2048), xw0, pa, 0, 0, 0);
        pa = __builtin_amdgcn_mfma_f32_32x32x16_bf16(
            *(const bf16x8*)(ub + (size_t)13 * 2048), xw1, pa, 0, 0, 0);
        pa = __builtin_amdgcn_mfma_f32_32x32x16_bf16(
            *(const bf16x8*)(ub + (size_t)14 * 2048), xw2, pa, 0, 0, 0);
        pa = __builtin_amdgcn_mfma_f32_32x32x16_bf16(
            *(const bf16x8*)(ub + (size_t)15 * 2048), xw3, pa, 0, 0, 0);
        __builtin_amdgcn_s_setprio(0);
      }

      // gelu (5-op sigmoid form) -> pack -> 4x ds_write_b64 into Ps[c]
      // pa[4g+e] = P[r=rtA*32+lo][m = mt*32 + g*8 + hi*4 + e]
#pragma unroll
      for (int g = 0; g < 4; ++g) {
        float gv[4];
#pragma unroll
        for (int e = 0; e < 4; ++e) {
          float v = pa[g * 4 + e];
          float ex = __builtin_amdgcn_exp2f(2.4554670f * v);
          float r = __builtin_amdgcn_rcpf(ex + 1.0f);
          gv[e] = __builtin_fmaf(-v, r, v);
        }
        u32 w0, w1;
        asm("v_cvt_pk_bf16_f32 %0, %1, %2" : "=v"(w0) : "v"(gv[0]), "v"(gv[1]));
        asm("v_cvt_pk_bf16_f32 %0, %1, %2" : "=v"(w1) : "v"(gv[2]), "v"(gv[3]));
        uint2 pk; pk.x = w0; pk.y = w1;
        *(uint2*)(psW + (size_t)c * (BM * MB * 2) + (size_t)(mt * 4 + g) * 2048) = pk;
      }

      __builtin_amdgcn_sched_barrier(0);
      asm volatile("s_waitcnt lgkmcnt(0)" ::: "memory");   // Ps published
      asm volatile("s_waitcnt vmcnt(0)" ::: "memory");     // Us(i+1) landed
      __builtin_amdgcn_s_barrier();
      __builtin_amdgcn_sched_barrier(0);
    }
    // A-waves done (pre-out written by B-waves)
  } else {
    // ================= consumer (B): verbatim R15 =================
    const int wb  = w - 8;
    const int rtp = wb & 1;   // 64-row half
    const int dq  = wb >> 1;  // 64-d quarter
    const int tb  = tid - 512;

    f32x16 ca[2][2];   // [rt2][dt] 32x32 tiles: 64r x 64d -> 64 accum
#pragma unroll
    for (int rt2 = 0; rt2 < 2; ++rt2)
#pragma unroll
      for (int dt = 0; dt < 2; ++dt)
#pragma unroll
        for (int e = 0; e < 16; ++e)
          ca[rt2][dt][e] = 0.f;

    for (int i = 0; i < NCH; ++i) {
      const int c = i & 1;
      // stage Ds(i) -> buf c (B-threads, 4 insts)
      {
        const char* src = dnH + (size_t)i * 32768;
#pragma unroll
        for (int j = 0; j < 4; ++j) {
          int t = j * 512 + tb;
          __builtin_amdgcn_global_load_lds(
              (const __attribute__((address_space(1))) void*)(src + (size_t)t * 16),
              (__attribute__((address_space(3))) void*)((char*)&Ds[c][0] + (size_t)t * 16),
              16, 0, 0);
        }
      }

      // B(i-1): C += Ps[c^1] @ Ds[c^1]
      if (i > 0) {
        const char* psb = (const char*)&Ps[c ^ 1][0];
        const char* dsb = (const char*)&Ds[c ^ 1][0];
        __builtin_amdgcn_s_setprio(1);
#pragma unroll
        for (int ks = 0; ks < 4; ++ks) {
          const size_t khp = (size_t)(ks * 2 + hi);
          bf16x8 a0 = *(const bf16x8*)(psb + khp * 2048 + (size_t)(rtp * 64 + lo) * 16);
          bf16x8 a1 = *(const bf16x8*)(psb + khp * 2048 + (size_t)(rtp * 64 + 32 + lo) * 16);
#pragma unroll
          for (int dt = 0; dt < 2; ++dt) {
            bf16x8 bv = *(const bf16x8*)(dsb + khp * 4096 + (size_t)(dq * 64 + dt * 32 + lo) * 16);
            ca[0][dt] = __builtin_amdgcn_mfma_f32_32x32x16_bf16(a0, bv, ca[0][dt], 0, 0, 0);
            ca[1][dt] = __builtin_amdgcn_mfma_f32_32x32x16_bf16(a1, bv, ca[1][dt], 0, 0, 0);
          }
        }
        __builtin_amdgcn_s_setprio(0);
      }

      __builtin_amdgcn_sched_barrier(0);
      asm volatile("s_waitcnt vmcnt(0)" ::: "memory");     // Ds(i) landed
      __builtin_amdgcn_s_barrier();
      __builtin_amdgcn_sched_barrier(0);
    }

    // final B(NCH-1): Ps[1], Ds[1]
    {
      const int c = (NCH - 1) & 1;
      const char* psb = (const char*)&Ps[c][0];
      const char* dsb = (const char*)&Ds[c][0];
      __builtin_amdgcn_s_setprio(1);
#pragma unroll
      for (int ks = 0; ks < 4; ++ks) {
        const size_t khp = (size_t)(ks * 2 + hi);
        bf16x8 a0 = *(const bf16x8*)(psb + khp * 2048 + (size_t)(rtp * 64 + lo) * 16);
        bf16x8 a1 = *(const bf16x8*)(psb + khp * 2048 + (size_t)(rtp * 64 + 32 + lo) * 16);
#pragma unroll
        for (int dt = 0; dt < 2; ++dt) {
          bf16x8 bv = *(const bf16x8*)(dsb + khp * 4096 + (size_t)(dq * 64 + dt * 32 + lo) * 16);
          ca[0][dt] = __builtin_amdgcn_mfma_f32_32x32x16_bf16(a0, bv, ca[0][dt], 0, 0, 0);
          ca[1][dt] = __builtin_amdgcn_mfma_f32_32x32x16_bf16(a1, bv, ca[1][dt], 0, 0, 0);
        }
      }
      __builtin_amdgcn_s_setprio(0);
    }

    // epilogue: bf16 pre-out into the xp buffer (coalesced u16 stores).
    // C-layout 32x32: col d = lo, row = (reg&3) + 8*(reg>>2) + 4*hi.
#pragma unroll
    for (int rt2 = 0; rt2 < 2; ++rt2)
#pragma unroll
      for (int dt = 0; dt < 2; ++dt) {
        const int d = h * ND + dq * 64 + dt * 32 + lo;
#pragma unroll
        for (int reg = 0; reg < 16; ++reg) {
          int r = rtp * 64 + rt2 * 32 + (reg & 3) + 8 * (reg >> 2) + 4 * hi;
          xp[(size_t)(row0 + r) * 4096 + d] = f2bf(ca[rt2][dt][reg]);
        }
      }
  }
}

extern "C" void kernel_launch(void* const* d_in, const int* in_sizes, int n_in,
                              void* d_out, int out_size, void* d_ws, size_t ws_size,
                              hipStream_t stream) {
  const float* x    = (const float*)d_in[0];
  const float* up   = (const float*)d_in[1];
  const float* down = (const float*)d_in[2];
  const int* perm   = (const int*)d_in[3];
  const int* unperm = (const int*)d_in[4];
  float* out = (float*)d_out;

  u16* upF   = (u16*)d_ws;                                   // 8 MB
  u16* downF = upF + (size_t)NH * NM * ND;                   // 8 MB
  u16* xp    = downF + (size_t)NH * NM * ND;                 // 128 MB (xp, then pre-out)

  // weights -> fragment-granule order (one-time, coalesced tile transposes)
  prep_up<<<dim3(NM / 64, ND / 64, NH), 256, 0, stream>>>(up, upF);
  prep_down<<<dim3(NM / 64, ND / 64, NH), 256, 0, stream>>>(down, downF);
  // xp[b][i] = bf16(x[b][perm[i]])
  permute_x<<<NB, 1024, 0, stream>>>(x, perm, xp);
  // main fused MLP: 1024 thr (8 hybrid-X producers + 8 consumers), 160KB.
  mlp_fused<<<dim3(NB / BM, NH), 1024, 0, stream>>>(xp, upF, downF);
  // unpermute + bf16->fp32 cvt into the real output
  unpermute_cvt<<<NB, 1024, 0, stream>>>(xp, unperm, out);
}

// Round 22
// 482.190 us; speedup vs baseline: 1.0733x; 1.0376x over previous
//
#include <hip/hip_runtime.h>
#include <hip/hip_bf16.h>
#include <math.h>

#define NB 16384
#define NH 16
#define ND 256
#define NM 1024
#define BM 128           // rows per block
#define MB 64            // m-chunk
#define NCH (NM / MB)    // 16

typedef float f32x4 __attribute__((ext_vector_type(4)));
typedef float f32x16 __attribute__((ext_vector_type(16)));
typedef short bf16x8 __attribute__((ext_vector_type(8)));
typedef unsigned short u16;
typedef unsigned int u32;

__device__ __forceinline__ u16 f2bf(float f) {
  union { float f; unsigned u; } v; v.f = f;
  unsigned r = v.u + 0x7FFFu + ((v.u >> 16) & 1u);
  return (u16)(r >> 16);
}

// UpF[h]: granule byte off = mc*32768 + kh*1024 + m*16, kh in [0,32), m in [0,64)
//   elems e: up[h][kh*8+e][mc*64+m]   (up fp32 [H][256][1024])
__global__ __launch_bounds__(256) void prep_up(const float* __restrict__ src,
                                               u16* __restrict__ dst) {
  __shared__ float tile[64][65];
  const int h = blockIdx.z;
  const int m0 = blockIdx.x * 64, d0 = blockIdx.y * 64;
  const int tr = threadIdx.x >> 6, tc = threadIdx.x & 63;
  const float* s = src + (size_t)h * ND * NM;
#pragma unroll
  for (int i = 0; i < 16; ++i) {
    int r = i * 4 + tr;
    tile[r][tc] = s[(size_t)(d0 + r) * NM + m0 + tc];
  }
  __syncthreads();
  char* dh = (char*)dst + (size_t)h * NM * ND * 2;
#pragma unroll
  for (int g = 0; g < 2; ++g) {
    int gi = g * 256 + threadIdx.x;
    int kh_l = gi >> 6, m_l = gi & 63;
    bf16x8 o;
#pragma unroll
    for (int e = 0; e < 8; ++e) o[e] = (short)f2bf(tile[kh_l * 8 + e][m_l]);
    *(bf16x8*)(dh + (size_t)(m0 >> 6) * 32768 + (size_t)((d0 >> 3) + kh_l) * 1024 + m_l * 16) = o;
  }
}

// DownF[h]: granule byte off = mc*32768 + kh*4096 + d*16, kh in [0,8), d in [0,256)
//   elems e: down[h][mc*64+kh*8+e][d]   (down fp32 [H][1024][256])
__global__ __launch_bounds__(256) void prep_down(const float* __restrict__ src,
                                                 u16* __restrict__ dst) {
  __shared__ float tile[64][65];
  const int h = blockIdx.z;
  const int mc = blockIdx.x, d0 = blockIdx.y * 64;
  const int tr = threadIdx.x >> 6, tc = threadIdx.x & 63;
  const float* s = src + (size_t)h * NM * ND;
#pragma unroll
  for (int i = 0; i < 16; ++i) {
    int r = i * 4 + tr;
    tile[r][tc] = s[(size_t)(mc * 64 + r) * ND + d0 + tc];
  }
  __syncthreads();
  char* dh = (char*)dst + (size_t)h * NM * ND * 2;
#pragma unroll
  for (int g = 0; g < 2; ++g) {
    int gi = g * 256 + threadIdx.x;
    int kh_l = gi >> 6, d_l = gi & 63;
    bf16x8 o;
#pragma unroll
    for (int e = 0; e < 8; ++e) o[e] = (short)f2bf(tile[kh_l * 8 + e][d_l]);
    *(bf16x8*)(dh + (size_t)mc * 32768 + (size_t)kh_l * 4096 + (size_t)(d0 + d_l) * 16) = o;
  }
}

// xp[b][i] = bf16(x[b][perm[i]])
__global__ __launch_bounds__(1024) void permute_x(const float* __restrict__ x,
                                                  const int* __restrict__ perm,
                                                  u16* __restrict__ xp) {
  const int b = blockIdx.x;
  const int t = threadIdx.x;
  const float* xr = x + (size_t)b * 4096;
  int4 p = *(const int4*)(perm + t * 4);
  ushort4 o;
  o.x = f2bf(xr[p.x]); o.y = f2bf(xr[p.y]);
  o.z = f2bf(xr[p.z]); o.w = f2bf(xr[p.w]);
  *(ushort4*)(xp + (size_t)b * 4096 + t * 4) = o;
}

// out[b][j] = fp32(pre[b][unperm[j]]); pre is the bf16 pre-unpermute output
// that mlp_fused wrote back into the xp buffer.
__global__ __launch_bounds__(1024) void unpermute_cvt(const u16* __restrict__ pre,
                                                      const int* __restrict__ unperm,
                                                      float* __restrict__ out) {
  __shared__ u16 row[4096];
  const int b = blockIdx.x;
  const int t = threadIdx.x;
  const u16* prow = pre + (size_t)b * 4096;
  *(ushort4*)(row + t * 4) = *(const ushort4*)(prow + t * 4);
  __syncthreads();
  int4 u = *(const int4*)(unperm + t * 4);
  f32x4 v;
  union { u32 u; float f; } c0, c1, c2, c3;
  c0.u = (u32)row[u.x] << 16; c1.u = (u32)row[u.y] << 16;
  c2.u = (u32)row[u.z] << 16; c3.u = (u32)row[u.w] << 16;
  v.x = c0.f; v.y = c1.f; v.z = c2.f; v.w = c3.f;
  *(f32x4*)(out + (size_t)b * 4096 + t * 4) = v;
}

// 16-wave PRODUCER/CONSUMER MLP -- R21 (347us, clean) + ROLE REBALANCE:
// all weight staging moved to B-waves (Us(i+1) AND Ds(i), 8 insts/thread).
// A was the region long pole (16 reads + 8 L2 X-loads + chain-16 MFMA +
// GELU + 4 staging + trailing vmcnt(0) that could stall on its own fresh
// staging); B finished early and idled at the barrier. Now:
//  - A loses 4 VMEM issues + addressing, and its vmcnt(0) is DELETED:
//    A's own xv/xw loads are auto-waited at consumption, and Us(i+1)'s
//    arrival is guaranteed by B's vmcnt(0)+barrier (A reads it only in
//    the NEXT region, after that barrier).
//  - B (short pole) gains 4 VMEM issues -- free.
// Barrier counts equal in both branches; buffer parities unchanged.
// GELU: 5-op sigmoid form (R21). Hybrid X residency (R19): xr[8] resident,
// K-high-half re-loaded from L2 each chunk in two pinned groups of 4.
__global__ __launch_bounds__(1024, 4) void mlp_fused(
    u16* __restrict__ xp,
    const u16* __restrict__ upF,
    const u16* __restrict__ downF) {
  __shared__ __align__(16) u16 Us[2][MB * ND];   // 2x32KB [kh32][m64][8]
  __shared__ __align__(16) u16 Ds[2][ND * MB];   // 2x32KB [kh8][d256][8]
  __shared__ __align__(16) u16 Ps[2][BM * MB];   // 2x16KB [kh8][r128][8]

  const int h   = blockIdx.y;
  const int rb  = blockIdx.x;
  const int tid = threadIdx.x;
  const int w   = tid >> 6;
  const int l   = tid & 63;
  const int lo  = l & 31;
  const int hi  = l >> 5;
  const int row0 = rb * BM;

  const char* upH = (const char*)upF + (size_t)h * NM * ND * 2;
  const char* dnH = (const char*)downF + (size_t)h * NM * ND * 2;

  // ---- prologue: all 16 waves stage Us(0) (2 insts/thread), then barrier
  {
#pragma unroll
    for (int i = 0; i < 2; ++i) {
      int t = i * 1024 + tid;
      __builtin_amdgcn_global_load_lds(
          (const __attribute__((address_space(1))) void*)(upH + (size_t)t * 16),
          (__attribute__((address_space(3))) void*)((char*)&Us[0][0] + (size_t)t * 16),
          16, 0, 0);
    }
  }
  asm volatile("s_waitcnt vmcnt(0)" ::: "memory");
  __builtin_amdgcn_s_barrier();

  if (w < 8) {
    // ================= producer (A): 32x32x16, hybrid X =================
    const int rtA = w & 3;    // 32-row tile
    const int mt  = w >> 2;   // 32-m tile of the 64-m chunk

    // X row base (global): lane = x-row (rtA*32+lo); k = ks*16 + hi*8 + e.
    const char* const px =
        (const char*)(xp + (size_t)(row0 + rtA * 32 + lo) * 4096 + h * ND);
    // Resident low-half fragments: ks = 0..7. 32 VGPR.
    bf16x8 xr[8];
#pragma unroll
    for (int ks = 0; ks < 8; ++ks)
      xr[ks] = *(const bf16x8*)(px + ks * 32 + hi * 16);

    char* const psW = (char*)&Ps[0][0] + (size_t)(rtA * 32 + lo) * 16 + hi * 8;

    for (int i = 0; i < NCH; ++i) {
      const int c = i & 1;

      // high-half X group 1 (ks 8..11) -- L2-resident repeats
      bf16x8 xv0 = *(const bf16x8*)(px + 8 * 32 + hi * 16);
      bf16x8 xv1 = *(const bf16x8*)(px + 9 * 32 + hi * 16);
      bf16x8 xv2 = *(const bf16x8*)(px + 10 * 32 + hi * 16);
      bf16x8 xv3 = *(const bf16x8*)(px + 11 * 32 + hi * 16);

      // A(i): P^T[32m x 32r] = Up-frags @ X-frags, chain-16 (R19-proven)
      f32x16 pa;
#pragma unroll
      for (int e = 0; e < 16; ++e) pa[e] = 0.f;
      {
        const char* ub = (const char*)&Us[c][0] + (size_t)(mt * 32 + lo) * 16 + hi * 1024;
        __builtin_amdgcn_s_setprio(1);
#pragma unroll
        for (int ks = 0; ks < 8; ++ks) {
          bf16x8 av = *(const bf16x8*)(ub + (size_t)ks * 2048);
          pa = __builtin_amdgcn_mfma_f32_32x32x16_bf16(av, xr[ks], pa, 0, 0, 0);
        }
        // group-1 high half (compiler inserts counted vmcnt before first use)
        pa = __builtin_amdgcn_mfma_f32_32x32x16_bf16(
            *(const bf16x8*)(ub + (size_t)8 * 2048), xv0, pa, 0, 0, 0);
        pa = __builtin_amdgcn_mfma_f32_32x32x16_bf16(
            *(const bf16x8*)(ub + (size_t)9 * 2048), xv1, pa, 0, 0, 0);
        pa = __builtin_amdgcn_mfma_f32_32x32x16_bf16(
            *(const bf16x8*)(ub + (size_t)10 * 2048), xv2, pa, 0, 0, 0);
        pa = __builtin_amdgcn_mfma_f32_32x32x16_bf16(
            *(const bf16x8*)(ub + (size_t)11 * 2048), xv3, pa, 0, 0, 0);
        // group-2 loads pinned here (caps live xv at 4 -> arch fits)
        __builtin_amdgcn_sched_barrier(0);
        bf16x8 xw0 = *(const bf16x8*)(px + 12 * 32 + hi * 16);
        bf16x8 xw1 = *(const bf16x8*)(px + 13 * 32 + hi * 16);
        bf16x8 xw2 = *(const bf16x8*)(px + 14 * 32 + hi * 16);
        bf16x8 xw3 = *(const bf16x8*)(px + 15 * 32 + hi * 16);
        pa = __builtin_amdgcn_mfma_f32_32x32x16_bf16(
            *(const bf16x8*)(ub + (size_t)12 * 2048), xw0, pa, 0, 0, 0);
        pa = __builtin_amdgcn_mfma_f32_32x32x16_bf16(
            *(const bf16x8*)(ub + (size_t)13 * 2048), xw1, pa, 0, 0, 0);
        pa = __builtin_amdgcn_mfma_f32_32x32x16_bf16(
            *(const bf16x8*)(ub + (size_t)14 * 2048), xw2, pa, 0, 0, 0);
        pa = __builtin_amdgcn_mfma_f32_32x32x16_bf16(
            *(const bf16x8*)(ub + (size_t)15 * 2048), xw3, pa, 0, 0, 0);
        __builtin_amdgcn_s_setprio(0);
      }

      // gelu (5-op sigmoid form) -> pack -> 4x ds_write_b64 into Ps[c]
      // pa[4g+e] = P[r=rtA*32+lo][m = mt*32 + g*8 + hi*4 + e]
#pragma unroll
      for (int g = 0; g < 4; ++g) {
        float gv[4];
#pragma unroll
        for (int e = 0; e < 4; ++e) {
          float v = pa[g * 4 + e];
          float ex = __builtin_amdgcn_exp2f(2.4554670f * v);
          float r = __builtin_amdgcn_rcpf(ex + 1.0f);
          gv[e] = __builtin_fmaf(-v, r, v);
        }
        u32 w0, w1;
        asm("v_cvt_pk_bf16_f32 %0, %1, %2" : "=v"(w0) : "v"(gv[0]), "v"(gv[1]));
        asm("v_cvt_pk_bf16_f32 %0, %1, %2" : "=v"(w1) : "v"(gv[2]), "v"(gv[3]));
        uint2 pk; pk.x = w0; pk.y = w1;
        *(uint2*)(psW + (size_t)c * (BM * MB * 2) + (size_t)(mt * 4 + g) * 2048) = pk;
      }

      // A-end: publish Ps (DS only). No vmcnt: A has no staging in flight;
      // Us(i+1) arrival is guaranteed by B's vmcnt(0) before this barrier.
      __builtin_amdgcn_sched_barrier(0);
      asm volatile("s_waitcnt lgkmcnt(0)" ::: "memory");
      __builtin_amdgcn_s_barrier();
      __builtin_amdgcn_sched_barrier(0);
    }
    // A-waves done (pre-out written by B-waves)
  } else {
    // ================= consumer (B): stages BOTH weight buffers ==========
    const int wb  = w - 8;
    const int rtp = wb & 1;   // 64-row half
    const int dq  = wb >> 1;  // 64-d quarter
    const int tb  = tid - 512;

    f32x16 ca[2][2];   // [rt2][dt] 32x32 tiles: 64r x 64d -> 64 accum
#pragma unroll
    for (int rt2 = 0; rt2 < 2; ++rt2)
#pragma unroll
      for (int dt = 0; dt < 2; ++dt)
#pragma unroll
        for (int e = 0; e < 16; ++e)
          ca[rt2][dt][e] = 0.f;

    for (int i = 0; i < NCH; ++i) {
      const int c = i & 1;
      // stage Ds(i) -> buf c  AND  Us(i+1) -> buf c^1 (8 insts/thread)
      {
        const char* srcD = dnH + (size_t)i * 32768;
#pragma unroll
        for (int j = 0; j < 4; ++j) {
          int t = j * 512 + tb;
          __builtin_amdgcn_global_load_lds(
              (const __attribute__((address_space(1))) void*)(srcD + (size_t)t * 16),
              (__attribute__((address_space(3))) void*)((char*)&Ds[c][0] + (size_t)t * 16),
              16, 0, 0);
        }
        if (i + 1 < NCH) {
          const char* srcU = upH + (size_t)(i + 1) * 32768;
#pragma unroll
          for (int j = 0; j < 4; ++j) {
            int t = j * 512 + tb;
            __builtin_amdgcn_global_load_lds(
                (const __attribute__((address_space(1))) void*)(srcU + (size_t)t * 16),
                (__attribute__((address_space(3))) void*)((char*)&Us[c ^ 1][0] + (size_t)t * 16),
                16, 0, 0);
          }
        }
      }

      // B(i-1): C += Ps[c^1] @ Ds[c^1]
      if (i > 0) {
        const char* psb = (const char*)&Ps[c ^ 1][0];
        const char* dsb = (const char*)&Ds[c ^ 1][0];
        __builtin_amdgcn_s_setprio(1);
#pragma unroll
        for (int ks = 0; ks < 4; ++ks) {
          const size_t khp = (size_t)(ks * 2 + hi);
          bf16x8 a0 = *(const bf16x8*)(psb + khp * 2048 + (size_t)(rtp * 64 + lo) * 16);
          bf16x8 a1 = *(const bf16x8*)(psb + khp * 2048 + (size_t)(rtp * 64 + 32 + lo) * 16);
#pragma unroll
          for (int dt = 0; dt < 2; ++dt) {
            bf16x8 bv = *(const bf16x8*)(dsb + khp * 4096 + (size_t)(dq * 64 + dt * 32 + lo) * 16);
            ca[0][dt] = __builtin_amdgcn_mfma_f32_32x32x16_bf16(a0, bv, ca[0][dt], 0, 0, 0);
            ca[1][dt] = __builtin_amdgcn_mfma_f32_32x32x16_bf16(a1, bv, ca[1][dt], 0, 0, 0);
          }
        }
        __builtin_amdgcn_s_setprio(0);
      }

      // B-end: drain staged Ds(i)/Us(i+1) so every wave past the barrier
      // may read them next region.
      __builtin_amdgcn_sched_barrier(0);
      asm volatile("s_waitcnt vmcnt(0)" ::: "memory");
      __builtin_amdgcn_s_barrier();
      __builtin_amdgcn_sched_barrier(0);
    }

    // final B(NCH-1): Ps[1], Ds[1]
    {
      const int c = (NCH - 1) & 1;
      const char* psb = (const char*)&Ps[c][0];
      const char* dsb = (const char*)&Ds[c][0];
      __builtin_amdgcn_s_setprio(1);
#pragma unroll
      for (int ks = 0; ks < 4; ++ks) {
        const size_t khp = (size_t)(ks * 2 + hi);
        bf16x8 a0 = *(const bf16x8*)(psb + khp * 2048 + (size_t)(rtp * 64 + lo) * 16);
        bf16x8 a1 = *(const bf16x8*)(psb + khp * 2048 + (size_t)(rtp * 64 + 32 + lo) * 16);
#pragma unroll
        for (int dt = 0; dt < 2; ++dt) {
          bf16x8 bv = *(const bf16x8*)(dsb + khp * 4096 + (size_t)(dq * 64 + dt * 32 + lo) * 16);
          ca[0][dt] = __builtin_amdgcn_mfma_f32_32x32x16_bf16(a0, bv, ca[0][dt], 0, 0, 0);
          ca[1][dt] = __builtin_amdgcn_mfma_f32_32x32x16_bf16(a1, bv, ca[1][dt], 0, 0, 0);
        }
      }
      __builtin_amdgcn_s_setprio(0);
    }

    // epilogue: bf16 pre-out into the xp buffer (coalesced u16 stores).
    // C-layout 32x32: col d = lo, row = (reg&3) + 8*(reg>>2) + 4*hi.
#pragma unroll
    for (int rt2 = 0; rt2 < 2; ++rt2)
#pragma unroll
      for (int dt = 0; dt < 2; ++dt) {
        const int d = h * ND + dq * 64 + dt * 32 + lo;
#pragma unroll
        for (int reg = 0; reg < 16; ++reg) {
          int r = rtp * 64 + rt2 * 32 + (reg & 3) + 8 * (reg >> 2) + 4 * hi;
          xp[(size_t)(row0 + r) * 4096 + d] = f2bf(ca[rt2][dt][reg]);
        }
      }
  }
}

extern "C" void kernel_launch(void* const* d_in, const int* in_sizes, int n_in,
                              void* d_out, int out_size, void* d_ws, size_t ws_size,
                              hipStream_t stream) {
  const float* x    = (const float*)d_in[0];
  const float* up   = (const float*)d_in[1];
  const float* down = (const float*)d_in[2];
  const int* perm   = (const int*)d_in[3];
  const int* unperm = (const int*)d_in[4];
  float* out = (float*)d_out;

  u16* upF   = (u16*)d_ws;                                   // 8 MB
  u16* downF = upF + (size_t)NH * NM * ND;                   // 8 MB
  u16* xp    = downF + (size_t)NH * NM * ND;                 // 128 MB (xp, then pre-out)

  // weights -> fragment-granule order (one-time, coalesced tile transposes)
  prep_up<<<dim3(NM / 64, ND / 64, NH), 256, 0, stream>>>(up, upF);
  prep_down<<<dim3(NM / 64, ND / 64, NH), 256, 0, stream>>>(down, downF);
  // xp[b][i] = bf16(x[b][perm[i]])
  permute_x<<<NB, 1024, 0, stream>>>(x, perm, xp);
  // main fused MLP: 1024 thr (8 producers + 8 staging-consumers), 160KB.
  mlp_fused<<<dim3(NB / BM, NH), 1024, 0, stream>>>(xp, upF, downF);
  // unpermute + bf16->fp32 cvt into the real output
  unpermute_cvt<<<NB, 1024, 0, stream>>>(xp, unperm, out);
}